// Round 16
// baseline (9212.141 us; speedup 1.0000x reference)
//
#include <hip/hip_runtime.h>

#define TT 2048
#define BB 64
#define INF 32
#define HH 512
#define OO 32

typedef __attribute__((ext_vector_type(8))) short bf16x8;   // 8 bf16 = 4 VGPR
typedef __attribute__((ext_vector_type(4))) float f32x4;    // MFMA acc

__device__ __forceinline__ float sigm(float x) {
  return 1.f / (1.f + __expf(-x));
}
__device__ __forceinline__ float tanh_(float x) {
  float e = __expf(2.f * x);
  return 1.f - 2.f / (1.f + e);
}
// fp32 -> bf16 round-to-nearest-even
__device__ __forceinline__ unsigned short f2bf(float f) {
  unsigned u = __float_as_uint(f);
  u = (u + 0x7FFFu + ((u >> 16) & 1u)) >> 16;
  return (unsigned short)u;
}
__device__ __forceinline__ float bf2f(unsigned short s) {
  return __uint_as_float(((unsigned)s) << 16);
}
// nearest bf16 whose LSB == par (error <= 1 bf16 ulp; works for both signs
// since the 2-ulp grid is uniform in raw-bit space)
__device__ __forceinline__ unsigned short f2bf_par(float f, unsigned par) {
  unsigned x = __float_as_uint(f);
  unsigned cand = ((x >> 17) << 1) | par;
  int diff = (int)(x - (cand << 16));
  if (diff > 0x10000) cand += 2;
  return (unsigned short)cand;
}

// Coherent (L1/L2-bypassing) 16B load from the coherence point (IF$).
#define COH_LOAD4(dst, ptr)                                                  \
  asm volatile("global_load_dwordx4 %0, %1, off sc0 sc1"                     \
               : "=v"(dst) : "v"(ptr))

#define SPIN_LIMIT 3000   // ~0.6 ms worst-case per wait; legit waits ~1-3 iters

#define HSTR 528   // bf16 row stride (R13-R15: conflicts ~0)

// grid = 256 WGs: bg = blockIdx&7 (8 batches), sl = blockIdx>>3 (16 h-idx).
// 512 thr = 8 waves. Compute mapping VALIDATED R13-R15 (gate-bundled rows,
// D: lane l reg r -> row=(l>>4)*4+r, col=l&15; in-lane i,f,g,o).
//
// R16 protocol — parity-tagged data, NO flags, NO barrier C:
//  * h exchanged via hring[3][64][512] bf16; every transmitted bf16 carries
//    LSB = t&1 (f2bf_par). Writer at iter t stores slot t%3 (u32 pairs,
//    relaxed agent scope, fire-and-forget).
//  * Reader at iter t polls ITS OWN 16B chunk of slot (t-1)%3 until all 8
//    LSBs == (t-1)&1 — the poll IS the data load (single IF$ RTT).
//  * 3-slot ring: stale occupant is 3 steps old (odd => opposite parity,
//    can't alias); writers at iter u touch slot u%3 while any concurrent
//    reader is at slot (u-1)%3 or (u-2)%3 (distinct mod 3).
//  * hlds double-buffered (buf t&1): stage(t+2) can only start after this
//    WG observed h_{t+1}, which requires its own mwave past A2(t+1), i.e.
//    ALL waves past A2(t+1), i.e. all reads of buf t&1 complete. => no C.
//  * Slot init (kernel_launch): byte patterns 0x01/0x00/0x01 make each
//    slot's parity invalid for its first read (also defeats 0xAA poison).
//
// RULE-20: all register-array indices compile-time constant after unroll.
__global__ __launch_bounds__(512, 2)
void lstm_fused(const float* __restrict__ X,
                const float* __restrict__ h0,
                const float* __restrict__ c0,
                const float* __restrict__ Wih,
                const float* __restrict__ Whh,
                const float* __restrict__ bih,
                const float* __restrict__ bhh,
                const float* __restrict__ Wout,
                const float* __restrict__ bout,
                float* __restrict__ outp,
                float* __restrict__ hT,
                float* __restrict__ cT,
                unsigned short* __restrict__ hring)  // [3][64][512] bf16+parity
{
  const int tid    = threadIdx.x;
  const int rg     = tid >> 6;
  const int lane   = tid & 63;
  const int bg     = blockIdx.x & 7;
  const int sl     = blockIdx.x >> 3;
  const int bglob0 = bg << 3;

  __shared__ __align__(16) unsigned short hlds[2][8 * HSTR]; // double-buffered

  const bool mwave = (rg < 4);

  // ---- per-wave persistent fragments (gate-bundled row permutation) ----
  bf16x8 aW[16], aX;
  float biasf[4];
  if (mwave) {
    const int ri = lane & 15;
    const int arow = ((ri & 3) << 9) + (sl << 4) + (rg << 2) + (ri >> 2);
    const float* wb = Whh + (size_t)arow * HH + ((lane >> 4) << 3);
#pragma unroll
    for (int kt = 0; kt < 16; ++kt) {
      float4 a = ((const float4*)(wb + kt * 32))[0];
      float4 b = ((const float4*)(wb + kt * 32))[1];
      bf16x8 f;
      f[0] = (short)f2bf(a.x); f[1] = (short)f2bf(a.y);
      f[2] = (short)f2bf(a.z); f[3] = (short)f2bf(a.w);
      f[4] = (short)f2bf(b.x); f[5] = (short)f2bf(b.y);
      f[6] = (short)f2bf(b.z); f[7] = (short)f2bf(b.w);
      aW[kt] = f;
    }
    const float* wi = Wih + (size_t)arow * INF + ((lane >> 4) << 3);
    float4 a = ((const float4*)wi)[0];
    float4 b = ((const float4*)wi)[1];
    aX[0] = (short)f2bf(a.x); aX[1] = (short)f2bf(a.y);
    aX[2] = (short)f2bf(a.z); aX[3] = (short)f2bf(a.w);
    aX[4] = (short)f2bf(b.x); aX[5] = (short)f2bf(b.y);
    aX[6] = (short)f2bf(b.z); aX[7] = (short)f2bf(b.w);
#pragma unroll
    for (int r = 0; r < 4; ++r) {
      int grow = (r << 9) + (sl << 4) + (rg << 2) + (lane >> 4);
      biasf[r] = bih[grow] + bhh[grow];
    }
  }
  float wout[8];
  {
    const float4* wp = (const float4*)(Wout + sl * HH + (lane << 3));
    float4 a = wp[0], b4 = wp[1];
    wout[0] = a.x;  wout[1] = a.y;  wout[2] = a.z;  wout[3] = a.w;
    wout[4] = b4.x; wout[5] = b4.y; wout[6] = b4.z; wout[7] = b4.w;
  }
  const float bo = bout[sl];

  // owner lanes: mwave && (lane&15)<8 -> (jj = 4rg + (lane>>4), b = lane&7)
  const bool owner = mwave && ((lane & 15) < 8);
  const int ob = lane & 7;
  const int ojj = (rg << 2) + (lane >> 4);
  const int hoff_owner = (bglob0 + ob) * HH + (sl << 4) + ojj;
  float cst = owner ? c0[hoff_owner] : 0.f;

  const int lb = tid >> 6, lg = tid & 63;   // cooperative-stage mapping

  int rslot = 2, wslot = 0;  // at iter t: rslot=(t-1)%3 (t>=1), wslot=t%3

  for (int t = 0; t < TT; ++t) {
    const int rbuf = t & 1;

    // ---- x prefetch + bf16 convert (h-independent; hidden under poll) ----
    bf16x8 bx;
    if (mwave) {
      const float* xr = X + (size_t)t * BB * INF + (bglob0 + (lane & 7)) * INF
                        + ((lane >> 4) << 3);
      float4 xva = ((const float4*)xr)[0];
      float4 xvb = ((const float4*)xr)[1];
      bx[0] = (short)f2bf(xva.x); bx[1] = (short)f2bf(xva.y);
      bx[2] = (short)f2bf(xva.z); bx[3] = (short)f2bf(xva.w);
      bx[4] = (short)f2bf(xvb.x); bx[5] = (short)f2bf(xvb.y);
      bx[6] = (short)f2bf(xvb.z); bx[7] = (short)f2bf(xvb.w);
    }

    // ---- poll+stage: the parity poll IS the data load (single RTT) ----
    if (t == 0) {
      const float* hp = h0 + (size_t)(bglob0 + lb) * HH + (lg << 3);
      float4 a = ((const float4*)hp)[0];
      float4 b = ((const float4*)hp)[1];
      unsigned d0 = (unsigned)f2bf(a.x) | ((unsigned)f2bf(a.y) << 16);
      unsigned d1 = (unsigned)f2bf(a.z) | ((unsigned)f2bf(a.w) << 16);
      unsigned d2 = (unsigned)f2bf(b.x) | ((unsigned)f2bf(b.y) << 16);
      unsigned d3 = (unsigned)f2bf(b.z) | ((unsigned)f2bf(b.w) << 16);
      *(int4*)(&hlds[rbuf][lb * HSTR + (lg << 3)]) = make_int4(d0, d1, d2, d3);
    } else {
      const unsigned short* src = hring + (size_t)rslot * BB * HH
                                  + (size_t)(bglob0 + lb) * HH + (lg << 3);
      const unsigned pp = ((t - 1) & 1) ? 0x00010001u : 0u;
      int4 hv;
      int guard = 0;
      for (;;) {
        COH_LOAD4(hv, src);
        asm volatile("s_waitcnt vmcnt(0)" ::: "memory");
        __builtin_amdgcn_sched_barrier(0);
        bool ok = ((((unsigned)hv.x ^ pp) & 0x00010001u) == 0u) &
                  ((((unsigned)hv.y ^ pp) & 0x00010001u) == 0u) &
                  ((((unsigned)hv.z ^ pp) & 0x00010001u) == 0u) &
                  ((((unsigned)hv.w ^ pp) & 0x00010001u) == 0u);
        if (__all(ok) || ++guard > SPIN_LIMIT) break;
      }
      *(int4*)(&hlds[rbuf][lb * HSTR + (lg << 3)]) = hv;
    }
    __syncthreads();  // A2: staged h visible; only barrier in the loop

    if (mwave) {
      // ---- 4 gates for jj in {4rg..4rg+3}: 17 MFMAs, 2 indep chains ----
      f32x4 acc0 = {0.f, 0.f, 0.f, 0.f};
      f32x4 acc1 = {0.f, 0.f, 0.f, 0.f};
      acc0 = __builtin_amdgcn_mfma_f32_16x16x32_bf16(aX, bx, acc0, 0, 0, 0);
      const unsigned short* hb = &hlds[rbuf][(lane & 7) * HSTR + ((lane >> 4) << 3)];
#pragma unroll
      for (int kt = 0; kt < 16; kt += 2) {
        bf16x8 bf0 = *(const bf16x8*)(hb + kt * 32);
        bf16x8 bf1 = *(const bf16x8*)(hb + (kt + 1) * 32);
        acc0 = __builtin_amdgcn_mfma_f32_16x16x32_bf16(aW[kt], bf0, acc0, 0, 0, 0);
        acc1 = __builtin_amdgcn_mfma_f32_16x16x32_bf16(aW[kt + 1], bf1, acc1, 0, 0, 0);
      }
      // ---- in-lane gates -> c/h update -> parity-tagged publish ----
      float i_ = sigm(acc0[0] + acc1[0] + biasf[0]);
      float f_ = sigm(acc0[1] + acc1[1] + biasf[1]);
      float g_ = tanh_(acc0[2] + acc1[2] + biasf[2]);
      float o_ = sigm(acc0[3] + acc1[3] + biasf[3]);
      float cnew = __fmaf_rn(f_, cst, i_ * g_);
      float hv = o_ * tanh_(cnew);
      if (owner) cst = cnew;
      float hv2 = __shfl(hv, (lane + 16) & 63, 64);  // partner jj_off+1
      if (owner && ((lane >> 4) & 1) == 0) {
        const unsigned par = (unsigned)(t & 1);
        unsigned pk = (unsigned)f2bf_par(hv, par)
                    | ((unsigned)f2bf_par(hv2, par) << 16);
        unsigned* slot32 = (unsigned*)(hring + (size_t)wslot * BB * HH);
        __hip_atomic_store(
            &slot32[((bglob0 + ob) << 8) + (sl << 3) + (rg << 1) + (lane >> 5)],
            pk, __ATOMIC_RELAXED, __HIP_MEMORY_SCOPE_AGENT);
      }
      if (owner && t == TT - 1) { hT[hoff_owner] = hv; cT[hoff_owner] = cst; }
    } else {
      // ---- output projection for batches 2*(rg-4), +1 (h_{t-1}) ----
      const int wb2 = (rg - 4) << 1;
      const bf16x8 ha = *(const bf16x8*)(&hlds[rbuf][wb2 * HSTR + (lane << 3)]);
      const bf16x8 hc = *(const bf16x8*)(&hlds[rbuf][(wb2 + 1) * HSTR + (lane << 3)]);
      float o0 = 0.f, o1 = 0.f;
#pragma unroll
      for (int j = 0; j < 8; ++j) {
        o0 = __fmaf_rn(bf2f((unsigned short)ha[j]), wout[j], o0);
        o1 = __fmaf_rn(bf2f((unsigned short)hc[j]), wout[j], o1);
      }
#pragma unroll
      for (int s = 32; s >= 1; s >>= 1) {
        o0 += __shfl_xor(o0, s, 64);
        o1 += __shfl_xor(o1, s, 64);
      }
      if (t > 0 && lane == 0) {
        outp[(size_t)(t - 1) * BB * OO + (bglob0 + wb2) * OO + sl] = o0 + bo;
        outp[(size_t)(t - 1) * BB * OO + (bglob0 + wb2 + 1) * OO + sl] = o1 + bo;
      }
    }
    // no barrier C: double-buffered hlds + parity induction cover WAR/reuse
    rslot = wslot;
    wslot = (wslot == 2) ? 0 : wslot + 1;
  }

  // ---- final output projection for h_{TT-1} -> outputs[TT-1] ----
  {
    // rslot == (TT-1)%3 here
    const unsigned short* src = hring + (size_t)rslot * BB * HH
                                + (size_t)(bglob0 + rg) * HH + (lane << 3);
    const unsigned pp = ((TT - 1) & 1) ? 0x00010001u : 0u;
    int4 p;
    int guard = 0;
    for (;;) {
      COH_LOAD4(p, src);
      asm volatile("s_waitcnt vmcnt(0)" ::: "memory");
      __builtin_amdgcn_sched_barrier(0);
      bool ok = ((((unsigned)p.x ^ pp) & 0x00010001u) == 0u) &
                ((((unsigned)p.y ^ pp) & 0x00010001u) == 0u) &
                ((((unsigned)p.z ^ pp) & 0x00010001u) == 0u) &
                ((((unsigned)p.w ^ pp) & 0x00010001u) == 0u);
      if (__all(ok) || ++guard > SPIN_LIMIT) break;
    }
    float oacc =
        __uint_as_float(((unsigned)p.x) << 16)         * wout[0] +
        __uint_as_float(((unsigned)p.x) & 0xFFFF0000u) * wout[1] +
        __uint_as_float(((unsigned)p.y) << 16)         * wout[2] +
        __uint_as_float(((unsigned)p.y) & 0xFFFF0000u) * wout[3] +
        __uint_as_float(((unsigned)p.z) << 16)         * wout[4] +
        __uint_as_float(((unsigned)p.z) & 0xFFFF0000u) * wout[5] +
        __uint_as_float(((unsigned)p.w) << 16)         * wout[6] +
        __uint_as_float(((unsigned)p.w) & 0xFFFF0000u) * wout[7];
#pragma unroll
    for (int s = 32; s >= 1; s >>= 1) oacc += __shfl_xor(oacc, s, 64);
    if (lane == 0)
      outp[(size_t)(TT - 1) * BB * OO + (bglob0 + rg) * OO + sl] = oacc + bo;
  }
}

extern "C" void kernel_launch(void* const* d_in, const int* in_sizes, int n_in,
                              void* d_out, int out_size, void* d_ws, size_t ws_size,
                              hipStream_t stream) {
  const float* X    = (const float*)d_in[0];
  const float* h0   = (const float*)d_in[1];
  const float* c0   = (const float*)d_in[2];
  const float* Wih  = (const float*)d_in[3];
  const float* Whh  = (const float*)d_in[4];
  const float* bih  = (const float*)d_in[5];
  const float* bhh  = (const float*)d_in[6];
  const float* Wout = (const float*)d_in[7];
  const float* bout = (const float*)d_in[8];

  float* outp = (float*)d_out;                       // [T][B][OUT]
  float* hT   = outp + (size_t)TT * BB * OO;         // [B][H]
  float* cT   = hT + (size_t)BB * HH;                // [B][H]

  unsigned short* hring = (unsigned short*)d_ws;     // 3*64*512*2 = 192 KB

  // per-slot init: parity must be INVALID for each slot's first read
  // (slot0 first-read parity 0 -> init 0x01 bytes = parity 1;
  //  slot1 first-read parity 1 -> init 0x00 = parity 0;
  //  slot2 first-read parity 0 -> init 0x01). Also defeats 0xAA poison.
  const size_t slotB = (size_t)BB * HH * sizeof(unsigned short);
  hipMemsetAsync((char*)d_ws + 0 * slotB, 0x01, slotB, stream);
  hipMemsetAsync((char*)d_ws + 1 * slotB, 0x00, slotB, stream);
  hipMemsetAsync((char*)d_ws + 2 * slotB, 0x01, slotB, stream);

  lstm_fused<<<dim3(256), dim3(512), 0, stream>>>(
      X, h0, c0, Wih, Whh, bih, bhh, Wout, bout, outp, hT, cT, hring);
}

// Round 19
// 3918.478 us; speedup vs baseline: 2.3509x; 2.3509x over previous
//
#include <hip/hip_runtime.h>

#define TT 2048
#define BB 64
#define INF 32
#define HH 512
#define OO 32

typedef __attribute__((ext_vector_type(8))) short bf16x8;   // 8 bf16 = 4 VGPR
typedef __attribute__((ext_vector_type(4))) float f32x4;    // MFMA acc

__device__ __forceinline__ float sigm(float x) {
  return 1.f / (1.f + __expf(-x));
}
__device__ __forceinline__ float tanh_(float x) {
  float e = __expf(2.f * x);
  return 1.f - 2.f / (1.f + e);
}
// fp32 -> bf16 round-to-nearest-even
__device__ __forceinline__ unsigned short f2bf(float f) {
  unsigned u = __float_as_uint(f);
  u = (u + 0x7FFFu + ((u >> 16) & 1u)) >> 16;
  return (unsigned short)u;
}
__device__ __forceinline__ float bf2f(unsigned short s) {
  return __uint_as_float(((unsigned)s) << 16);
}

// Coherent (L1/L2-bypassing) 16B load from the coherence point (IF$).
// R18 FINDING: sc0-only (same-XCD L2) is NOT coherent for inter-WG exchange
// even when HW_REG_XCC_ID verifies co-residency — sc1 is mandatory.
#define COH_LOAD4(dst, ptr)                                                  \
  asm volatile("global_load_dwordx4 %0, %1, off sc0 sc1"                     \
               : "=v"(dst) : "v"(ptr))

#define SPIN_LIMIT 20000

#define HSTR 528   // bf16 row stride (R13-R15: conflicts ~0)

// grid = 256 WGs: bg = blockIdx&7 (8 batches), sl = blockIdx>>3 (16 h-idx).
// 512 thr = 8 waves. Compute mapping VALIDATED R13-R15 (gate-bundled rows,
// D: lane l reg r -> row=(l>>4)*4+r, col=l&15; in-lane i,f,g,o).
// Sync protocol = R15 local optimum (all-wave tiny-flag poll -> bulk stage
// -> A2 -> MFMA/gates/publish -> C -> flag). Refuted alternatives:
//   R9/R16 poll-is-data (FETCH storm), R12 no-barrier-C (+1.4ms),
//   R18 sc0-only same-XCD (stale reads). Do not resurrect.
//
// RULE-20: all register-array indices compile-time constant after unroll.
__global__ __launch_bounds__(512, 2)
void lstm_fused(const float* __restrict__ X,
                const float* __restrict__ h0,
                const float* __restrict__ c0,
                const float* __restrict__ Wih,
                const float* __restrict__ Whh,
                const float* __restrict__ bih,
                const float* __restrict__ bhh,
                const float* __restrict__ Wout,
                const float* __restrict__ bout,
                float* __restrict__ outp,
                float* __restrict__ hT,
                float* __restrict__ cT,
                unsigned short* __restrict__ hring,  // [2][64][512] bf16
                int* __restrict__ flags)             // [8][32] monotonic
{
  const int tid    = threadIdx.x;
  const int rg     = tid >> 6;
  const int lane   = tid & 63;
  const int bg     = blockIdx.x & 7;
  const int sl     = blockIdx.x >> 3;
  const int bglob0 = bg << 3;

  __shared__ __align__(16) unsigned short hlds[8 * HSTR]; // staged h bf16

  const bool mwave = (rg < 4);

  // ---- per-wave persistent fragments (gate-bundled row permutation) ----
  bf16x8 aW[16], aX;
  float biasf[4];
  if (mwave) {
    const int ri = lane & 15;
    const int arow = ((ri & 3) << 9) + (sl << 4) + (rg << 2) + (ri >> 2);
    const float* wb = Whh + (size_t)arow * HH + ((lane >> 4) << 3);
#pragma unroll
    for (int kt = 0; kt < 16; ++kt) {
      float4 a = ((const float4*)(wb + kt * 32))[0];
      float4 b = ((const float4*)(wb + kt * 32))[1];
      bf16x8 f;
      f[0] = (short)f2bf(a.x); f[1] = (short)f2bf(a.y);
      f[2] = (short)f2bf(a.z); f[3] = (short)f2bf(a.w);
      f[4] = (short)f2bf(b.x); f[5] = (short)f2bf(b.y);
      f[6] = (short)f2bf(b.z); f[7] = (short)f2bf(b.w);
      aW[kt] = f;
    }
    const float* wi = Wih + (size_t)arow * INF + ((lane >> 4) << 3);
    float4 a = ((const float4*)wi)[0];
    float4 b = ((const float4*)wi)[1];
    aX[0] = (short)f2bf(a.x); aX[1] = (short)f2bf(a.y);
    aX[2] = (short)f2bf(a.z); aX[3] = (short)f2bf(a.w);
    aX[4] = (short)f2bf(b.x); aX[5] = (short)f2bf(b.y);
    aX[6] = (short)f2bf(b.z); aX[7] = (short)f2bf(b.w);
#pragma unroll
    for (int r = 0; r < 4; ++r) {
      int grow = (r << 9) + (sl << 4) + (rg << 2) + (lane >> 4);
      biasf[r] = bih[grow] + bhh[grow];
    }
  }
  float wout[8];
  {
    const float4* wp = (const float4*)(Wout + sl * HH + (lane << 3));
    float4 a = wp[0], b4 = wp[1];
    wout[0] = a.x;  wout[1] = a.y;  wout[2] = a.z;  wout[3] = a.w;
    wout[4] = b4.x; wout[5] = b4.y; wout[6] = b4.z; wout[7] = b4.w;
  }
  const float bo = bout[sl];

  // owner lanes: mwave && (lane&15)<8 -> (jj = 4rg + (lane>>4), b = lane&7)
  const bool owner = mwave && ((lane & 15) < 8);
  const int ob = lane & 7;
  const int ojj = (rg << 2) + (lane >> 4);
  const int hoff_owner = (bglob0 + ob) * HH + (sl << 4) + ojj;
  float cst = owner ? c0[hoff_owner] : 0.f;

  const int lb = tid >> 6, lg = tid & 63;   // cooperative-stage mapping
  int* myflags = flags + (bg << 5);

  for (int t = 0; t < TT; ++t) {
    // ---- x prefetch + bf16 convert (h-independent; hidden under poll) ----
    bf16x8 bx;
    if (mwave) {
      const float* xr = X + (size_t)t * BB * INF + (bglob0 + (lane & 7)) * INF
                        + ((lane >> 4) << 3);
      float4 xva = ((const float4*)xr)[0];
      float4 xvb = ((const float4*)xr)[1];
      bx[0] = (short)f2bf(xva.x); bx[1] = (short)f2bf(xva.y);
      bx[2] = (short)f2bf(xva.z); bx[3] = (short)f2bf(xva.w);
      bx[4] = (short)f2bf(xvb.x); bx[5] = (short)f2bf(xvb.y);
      bx[6] = (short)f2bf(xvb.z); bx[7] = (short)f2bf(xvb.w);
    }

    // ---- ALL-WAVE poll for h_{t-1} (no barrier A) ----
    if (t > 0) {
      int f = __hip_atomic_load(&myflags[lane & 31], __ATOMIC_RELAXED,
                                __HIP_MEMORY_SCOPE_AGENT);
      int guard = 0;
      while (__any(f < t)) {
        if (++guard > SPIN_LIMIT) break;
        __builtin_amdgcn_s_sleep(1);
        f = __hip_atomic_load(&myflags[lane & 31], __ATOMIC_RELAXED,
                              __HIP_MEMORY_SCOPE_AGENT);
      }
    }

    // ---- cooperative stage of h_{t-1} (bf16, 8 KB once per WG) ----
    if (t == 0) {
      const float* hp = h0 + (size_t)(bglob0 + lb) * HH + (lg << 3);
      float4 a = ((const float4*)hp)[0];
      float4 b = ((const float4*)hp)[1];
      unsigned d0 = (unsigned)f2bf(a.x) | ((unsigned)f2bf(a.y) << 16);
      unsigned d1 = (unsigned)f2bf(a.z) | ((unsigned)f2bf(a.w) << 16);
      unsigned d2 = (unsigned)f2bf(b.x) | ((unsigned)f2bf(b.y) << 16);
      unsigned d3 = (unsigned)f2bf(b.z) | ((unsigned)f2bf(b.w) << 16);
      *(int4*)(hlds + lb * HSTR + (lg << 3)) = make_int4(d0, d1, d2, d3);
    } else {
      const unsigned short* hsrc = hring + (size_t)((t - 1) & 1) * BB * HH
                                   + (size_t)(bglob0 + lb) * HH + (lg << 3);
      int4 hv;
      COH_LOAD4(hv, hsrc);
      asm volatile("s_waitcnt vmcnt(0)" ::: "memory");
      __builtin_amdgcn_sched_barrier(0);
      *(int4*)(hlds + lb * HSTR + (lg << 3)) = hv;
    }
    __syncthreads();  // barrier A2: staged h visible to all waves

    float o0 = 0.f, o1 = 0.f;   // out-proj partials (waves 4-7)
    if (mwave) {
      // ---- 4 gates for jj in {4rg..4rg+3}: 17 MFMAs, 2 indep chains ----
      f32x4 acc0 = {0.f, 0.f, 0.f, 0.f};
      f32x4 acc1 = {0.f, 0.f, 0.f, 0.f};
      acc0 = __builtin_amdgcn_mfma_f32_16x16x32_bf16(aX, bx, acc0, 0, 0, 0);
      const unsigned short* hb = hlds + (lane & 7) * HSTR + ((lane >> 4) << 3);
#pragma unroll
      for (int kt = 0; kt < 16; kt += 2) {
        bf16x8 bf0 = *(const bf16x8*)(hb + kt * 32);
        bf16x8 bf1 = *(const bf16x8*)(hb + (kt + 1) * 32);
        acc0 = __builtin_amdgcn_mfma_f32_16x16x32_bf16(aW[kt], bf0, acc0, 0, 0, 0);
        acc1 = __builtin_amdgcn_mfma_f32_16x16x32_bf16(aW[kt + 1], bf1, acc1, 0, 0, 0);
      }
      // ---- in-lane gates -> c/h update -> packed bf16 publish ----
      float i_ = sigm(acc0[0] + acc1[0] + biasf[0]);
      float f_ = sigm(acc0[1] + acc1[1] + biasf[1]);
      float g_ = tanh_(acc0[2] + acc1[2] + biasf[2]);
      float o_ = sigm(acc0[3] + acc1[3] + biasf[3]);
      float cnew = __fmaf_rn(f_, cst, i_ * g_);
      float hv = o_ * tanh_(cnew);
      if (owner) cst = cnew;
      float hv2 = __shfl(hv, (lane + 16) & 63, 64);  // partner jj_off+1
      if (owner && ((lane >> 4) & 1) == 0) {
        unsigned pk = (unsigned)f2bf(hv) | ((unsigned)f2bf(hv2) << 16);
        unsigned* slot32 = (unsigned*)(hring + (size_t)(t & 1) * BB * HH);
        __hip_atomic_store(
            &slot32[((bglob0 + ob) << 8) + (sl << 3) + (rg << 1) + (lane >> 5)],
            pk, __ATOMIC_RELAXED, __HIP_MEMORY_SCOPE_AGENT);
      }
      if (owner && t == TT - 1) { hT[hoff_owner] = hv; cT[hoff_owner] = cst; }
    } else {
      // ---- output projection for batches 2*(rg-4), +1 (h_{t-1}) ----
      const int wb2 = (rg - 4) << 1;
      const bf16x8 ha = *(const bf16x8*)(hlds + wb2 * HSTR + (lane << 3));
      const bf16x8 hc = *(const bf16x8*)(hlds + (wb2 + 1) * HSTR + (lane << 3));
#pragma unroll
      for (int j = 0; j < 8; ++j) {
        o0 = __fmaf_rn(bf2f((unsigned short)ha[j]), wout[j], o0);
        o1 = __fmaf_rn(bf2f((unsigned short)hc[j]), wout[j], o1);
      }
#pragma unroll
      for (int s = 32; s >= 1; s >>= 1) {
        o0 += __shfl_xor(o0, s, 64);
        o1 += __shfl_xor(o1, s, 64);
      }
    }
    __syncthreads();  // barrier C: drains owners' h stores before flag
    if (tid == 0)
      __hip_atomic_store(&myflags[sl], t + 1, __ATOMIC_RELAXED,
                         __HIP_MEMORY_SCOPE_AGENT);
    // ---- deferred outp store (drains during next step's slack) ----
    if (!mwave && t > 0 && lane == 0) {
      const int wb2 = (rg - 4) << 1;
      outp[(size_t)(t - 1) * BB * OO + (bglob0 + wb2) * OO + sl] = o0 + bo;
      outp[(size_t)(t - 1) * BB * OO + (bglob0 + wb2 + 1) * OO + sl] = o1 + bo;
    }
  }

  // ---- final output projection for h_{TT-1} -> outputs[TT-1] ----
  {
    int f = __hip_atomic_load(&myflags[lane & 31], __ATOMIC_RELAXED,
                              __HIP_MEMORY_SCOPE_AGENT);
    int guard = 0;
    while (__any(f < TT)) {
      if (++guard > SPIN_LIMIT) break;
      __builtin_amdgcn_s_sleep(1);
      f = __hip_atomic_load(&myflags[lane & 31], __ATOMIC_RELAXED,
                            __HIP_MEMORY_SCOPE_AGENT);
    }
  }
  {
    const unsigned short* hb = hring + (size_t)((TT - 1) & 1) * BB * HH
                               + (size_t)(bglob0 + rg) * HH + (lane << 3);
    int4 p;
    COH_LOAD4(p, hb);
    asm volatile("s_waitcnt vmcnt(0)" ::: "memory");
    __builtin_amdgcn_sched_barrier(0);
    float oacc =
        __uint_as_float(((unsigned)p.x) << 16)         * wout[0] +
        __uint_as_float(((unsigned)p.x) & 0xFFFF0000u) * wout[1] +
        __uint_as_float(((unsigned)p.y) << 16)         * wout[2] +
        __uint_as_float(((unsigned)p.y) & 0xFFFF0000u) * wout[3] +
        __uint_as_float(((unsigned)p.z) << 16)         * wout[4] +
        __uint_as_float(((unsigned)p.z) & 0xFFFF0000u) * wout[5] +
        __uint_as_float(((unsigned)p.w) << 16)         * wout[6] +
        __uint_as_float(((unsigned)p.w) & 0xFFFF0000u) * wout[7];
#pragma unroll
    for (int s = 32; s >= 1; s >>= 1) oacc += __shfl_xor(oacc, s, 64);
    if (lane == 0)
      outp[(size_t)(TT - 1) * BB * OO + (bglob0 + rg) * OO + sl] = oacc + bo;
  }
}

extern "C" void kernel_launch(void* const* d_in, const int* in_sizes, int n_in,
                              void* d_out, int out_size, void* d_ws, size_t ws_size,
                              hipStream_t stream) {
  const float* X    = (const float*)d_in[0];
  const float* h0   = (const float*)d_in[1];
  const float* c0   = (const float*)d_in[2];
  const float* Wih  = (const float*)d_in[3];
  const float* Whh  = (const float*)d_in[4];
  const float* bih  = (const float*)d_in[5];
  const float* bhh  = (const float*)d_in[6];
  const float* Wout = (const float*)d_in[7];
  const float* bout = (const float*)d_in[8];

  float* outp = (float*)d_out;                       // [T][B][OUT]
  float* hT   = outp + (size_t)TT * BB * OO;         // [B][H]
  float* cT   = hT + (size_t)BB * HH;                // [B][H]

  unsigned short* hring = (unsigned short*)d_ws;     // 128 KB
  int* flags = (int*)((char*)d_ws + (size_t)2 * BB * HH * sizeof(unsigned short));

  // flags must be zero at every replay (graph-captured, runs each call)
  hipMemsetAsync(flags, 0, 8 * 32 * sizeof(int), stream);

  lstm_fused<<<dim3(256), dim3(512), 0, stream>>>(
      X, h0, c0, Wih, Whh, bih, bhh, Wout, bout, outp, hT, cT, hring, flags);
}